// Round 9
// baseline (18129.704 us; speedup 1.0000x reference)
//
#include <hip/hip_runtime.h>
#include <stdint.h>

#define T_MAIN 4096
#define T_TOT  5120

// ws dword offsets
#define O_W2   0            // 2*512*204 = 208896
#define O_W1   208896       // 512*80
#define O_W1B  249856       // 92*80
#define O_W3   257216       // 408*80 = 32640
#define O_WY   289856       // 2*32
#define O_X    289920       // 4096
#define O_H1T  294016       // 5121*152
#define O_H2AT 1072408      // 5121*126
#define O_H2BT 1717654      // 5121*125 -> end 2357779 dw (~9.4 MB)

typedef _Float16 f16;
typedef _Float16 f16x2 __attribute__((ext_vector_type(2)));

__device__ __forceinline__ float fdot2(uint32_t a, uint32_t b, float c) {
  return __builtin_amdgcn_fdot2(__builtin_bit_cast(f16x2, a),
                                __builtin_bit_cast(f16x2, b), c, false);
}
__device__ __forceinline__ uint32_t packf16(float a, float b) {
  f16x2 p = { (_Float16)a, (_Float16)b };
  return __builtin_bit_cast(uint32_t, p);
}
__device__ __forceinline__ uint16_t f16bits(float v) {
  return __builtin_bit_cast(uint16_t, (_Float16)v);
}
// AGPR accessors: force storage into the accumulator file (cannot spill; pins
// total reg demand so the allocator must run at 2 waves/EU with arch cap 256).
__device__ __forceinline__ uint32_t aput(uint32_t v) {
  uint32_t a;
  asm("v_accvgpr_write_b32 %0, %1" : "=a"(a) : "v"(v));
  return a;
}
__device__ __forceinline__ uint32_t aget(uint32_t a) {
  uint32_t v;
  asm("v_accvgpr_read_b32 %0, %1" : "=v"(v) : "a"(a));
  return v;
}
__device__ __forceinline__ float sigm(float x) { return 1.f / (1.f + __expf(-x)); }
__device__ __forceinline__ float tanhfast(float x) { return 2.f / (1.f + __expf(-2.f * x)) - 1.f; }

// ---------- prep: weight packing ----------
// L2 row layout (u16 slots [0,408)): [h1 k<151 |pad] [h2 units 0..125 |2pad] [h2 units 126..250 |3pad]
__device__ float l2w(int pw, int tid, int s, const float* Wih2, const float* Whh2) {
  int NGU = pw ? 125 : 126;
  if (tid >= 4 * NGU) return 0.f;
  int g = tid / NGU, u = tid - g * NGU, ug = pw ? 126 + u : u;
  int R = g * 251 + ug;
  if (s < 151) return Wih2[R * 151 + s];
  if (s < 152) return 0.f;
  if (s < 280) { int j = s - 152; return (j < 126) ? Whh2[R * 251 + j] : 0.f; }
  if (s < 408) { int j = s - 280; return (j < 125) ? Whh2[R * 251 + 126 + j] : 0.f; }
  return 0.f;
}
// L3 row layout (u16 slots [0,320)): [h2a 0..125|2pad][h2b 0..124|3pad][h3 0..50|13pad]
__device__ float l3w(int r3, int s, const float* Wih3, const float* Whh3) {
  if (s < 128) { return (s < 126) ? Wih3[r3 * 251 + s] : 0.f; }
  if (s < 256) { int j = s - 128; return (j < 125) ? Wih3[r3 * 251 + 126 + j] : 0.f; }
  if (s < 320) { int j = s - 256; return (j < 51) ? Whh3[r3 * 51 + j] : 0.f; }
  return 0.f;
}

__global__ void prep(const float* __restrict__ x,
                     const float* __restrict__ Wih1, const float* __restrict__ Whh1,
                     const float* __restrict__ Wih2, const float* __restrict__ Whh2,
                     const float* __restrict__ Wih3, const float* __restrict__ Whh3,
                     const float* __restrict__ Wl,
                     uint32_t* __restrict__ ws) {
  int b = blockIdx.x, lt = threadIdx.x;   // 64 threads
  if (b < 1024) {                          // L2 per-thread rows
    int pw = b >> 9, tid = b & 511;
    uint32_t* dst = ws + O_W2 + (size_t)(pw * 512 + tid) * 204;
    for (int d = lt; d < 204; d += 64)
      dst[d] = packf16(l2w(pw, tid, 2 * d, Wih2, Whh2),
                       l2w(pw, tid, 2 * d + 1, Wih2, Whh2));
  } else if (b < 1628) {                   // L1 rows (80-dw blocks: [xw][3 pad][19 uint4 h])
    int r = b - 1024;
    uint32_t* dst = ws + ((r < 512) ? (O_W1 + r * 80) : (O_W1B + (r - 512) * 80));
    for (int d = lt; d < 80; d += 64) {
      uint32_t v;
      if (d == 0)      v = packf16(Wih1[r * 2 + 0], Wih1[r * 2 + 1]);
      else if (d < 4)  v = 0u;
      else {
        int k0 = 2 * (d - 4), k1 = k0 + 1;
        v = packf16(k0 < 151 ? Whh1[r * 151 + k0] : 0.f,
                    k1 < 151 ? Whh1[r * 151 + k1] : 0.f);
      }
      dst[d] = v;
    }
  } else if (b < 2036) {                   // L3 half-rows (80 dw each = 160 u16 slots)
    int idx = b - 1628, r3 = idx >> 1, h = idx & 1;
    uint32_t* dst = ws + O_W3 + idx * 80;
    for (int d = lt; d < 80; d += 64) {
      int s0 = h * 160 + 2 * d;
      dst[d] = packf16(l3w(r3, s0, Wih3, Whh3), l3w(r3, s0 + 1, Wih3, Whh3));
    }
  } else if (b == 2036) {                  // Wl rows (2 x 32 dw over h3 slots [0,64))
    for (int d = lt; d < 64; d += 64) {
      int r = d >> 5, s0 = (d & 31) * 2;
      float v0 = (s0 < 51) ? Wl[r * 51 + s0] : 0.f;
      float v1 = (s0 + 1 < 51) ? Wl[r * 51 + s0 + 1] : 0.f;
      ws[O_WY + d] = packf16(v0, v1);
    }
  } else if (b == 2037) {                  // zero tag-slot 0 of each trace (tag 0 = initial state)
    for (int i = lt; i < 152; i += 64) ws[O_H1T + i] = 0u;
    for (int i = lt; i < 126; i += 64) ws[O_H2AT + i] = 0u;
    for (int i = lt; i < 125; i += 64) ws[O_H2BT + i] = 0u;
  } else {                                 // x -> f16 pairs
    int i = (b - 2038) * 64 + lt;
    if (i < T_MAIN) ws[O_X + i] = packf16(x[2 * i], x[2 * i + 1]);
  }
}

// ---------- tagged-slot primitives (relaxed agent atomics; tag+data in one dword) ----------
__device__ __forceinline__ uint32_t pollslot(uint32_t* p, uint32_t tag, volatile int* bail) {
  if (*bail) return 0u;
  tag &= 0xffffu;
  for (int i = 0; i < 4000000; ++i) {
    uint32_t v = __hip_atomic_load(p, __ATOMIC_RELAXED, __HIP_MEMORY_SCOPE_AGENT);
    if ((v & 0xffffu) == tag) return v;
    if ((i & 0xffff) == 0xffff && *bail) return 0u;
  }
  *bail = 1;                 // terminate instead of hanging (result garbage)
  return 0u;
}
__device__ __forceinline__ void pubslot(uint32_t* p, uint16_t bits, uint32_t tag) {
  __hip_atomic_store(p, ((uint32_t)bits << 16) | (tag & 0xffffu),
                     __ATOMIC_RELAXED, __HIP_MEMORY_SCOPE_AGENT);
}

__global__ __attribute__((amdgpu_flat_work_group_size(512, 512),
                          amdgpu_waves_per_eu(2, 2)))
void lstm3(
    uint32_t* __restrict__ ws,
    const float* __restrict__ bih1, const float* __restrict__ bhh1,
    const float* __restrict__ bih2, const float* __restrict__ bhh2,
    const float* __restrict__ bih3, const float* __restrict__ bhh3,
    const float* __restrict__ bl, float* __restrict__ out) {
  const int bid = blockIdx.x;
  if ((bid & 7) != 1) return;          // active blocks: 1, 9, 17 (same XCD under %8 round-robin)
  const int wg = bid >> 3;             // 0, 1, 2
  const int tid = threadIdx.x;
  __shared__ float G[604];
  __shared__ __align__(16) uint16_t Vbuf[408];   // pair: [h1 152][h2a 128][h2b 128]
  __shared__ __align__(16) uint16_t h1L[152];    // wg0: local h1 (f16)
  __shared__ __align__(16) uint16_t Vb3[320];    // wg0: [h2a 128][h2b 128][h3 64]
  __shared__ uint32_t yL;
  __shared__ int bailS;
  if (tid == 0) { bailS = 0; yL = 0u; }

  if (wg >= 1) {
    // ================= L2 pair (wg 1: units 0..125 ; wg 2: units 126..250) =================
    const int pw = wg - 1;
    const int NGU = pw ? 125 : 126;
    const int NG = 4 * NGU;
    const int OWN = pw ? 280 : 152;
    const int REM = pw ? 152 : 280;
    const int NREM = pw ? 126 : 125;
    uint32_t* const ownT = ws + (pw ? O_H2BT : O_H2AT);
    uint32_t* const remT = ws + (pw ? O_H2AT : O_H2BT);
    const int ownStr = pw ? 125 : 126;
    const int remStr = pw ? 126 : 125;

    uint32_t W2lo[100];        // arch-VGPR resident (j<25)
    uint32_t W2hi[104];        // AGPR resident (j=25..50), forced via v_accvgpr_write
    {
      const uint32_t* src = ws + O_W2 + (size_t)(pw * 512 + tid) * 204;
#pragma unroll
      for (int i = 0; i < 100; ++i) W2lo[i] = src[i];
#pragma unroll
      for (int i = 0; i < 104; ++i) W2hi[i] = aput(src[100 + i]);
    }
    float bias = 0.f;
    if (tid < NG) {
      int g = tid / NGU, u = tid - g * NGU, ug = pw ? 126 + u : u;
      int R = g * 251 + ug;
      bias = bih2[R] + bhh2[R];
    }
    float c2 = 0.f;
    if (tid < 408) Vbuf[tid] = 0;
    __syncthreads();

#pragma unroll 1
    for (int t = 0; t < T_TOT; ++t) {
      // stage: h1(t) (slot t+1) + partner half h2(t-1) (slot t)
      if (tid < 151) {
        uint32_t v = pollslot(ws + O_H1T + (size_t)(t + 1) * 152 + tid, (uint32_t)(t + 1), &bailS);
        Vbuf[tid] = (uint16_t)(v >> 16);
      } else if (tid >= 160 && tid < 160 + NREM) {
        int j = tid - 160;
        uint32_t v = pollslot(remT + (size_t)t * remStr + j, (uint32_t)t, &bailS);
        Vbuf[REM + j] = (uint16_t)(v >> 16);
      }
      __syncthreads();
      // gates: 1 thread = 1 gate row, 51 uint4
      if (tid < NG) {
        const uint4* V = (const uint4*)Vbuf;
        float g0 = bias, g1 = 0.f, g2 = 0.f, g3 = 0.f;
#pragma unroll
        for (int j = 0; j < 25; ++j) {
          uint4 hv = V[j];
          g0 = fdot2(W2lo[4 * j + 0], hv.x, g0);
          g1 = fdot2(W2lo[4 * j + 1], hv.y, g1);
          g2 = fdot2(W2lo[4 * j + 2], hv.z, g2);
          g3 = fdot2(W2lo[4 * j + 3], hv.w, g3);
        }
#pragma unroll
        for (int j = 25; j < 51; ++j) {
          uint4 hv = V[j];
          g0 = fdot2(aget(W2hi[4 * (j - 25) + 0]), hv.x, g0);
          g1 = fdot2(aget(W2hi[4 * (j - 25) + 1]), hv.y, g1);
          g2 = fdot2(aget(W2hi[4 * (j - 25) + 2]), hv.z, g2);
          g3 = fdot2(aget(W2hi[4 * (j - 25) + 3]), hv.w, g3);
        }
        G[tid] = (g0 + g1) + (g2 + g3);
      }
      __syncthreads();
      // cell + publish own half (tagged, fire-and-forget)
      if (tid < NGU) {
        float gi = sigm(G[tid]), gf = sigm(G[NGU + tid]);
        float gg = tanhfast(G[2 * NGU + tid]), go = sigm(G[3 * NGU + tid]);
        c2 = gf * c2 + gi * gg;
        uint16_t bits = f16bits(go * tanhfast(c2));
        Vbuf[OWN + tid] = bits;
        pubslot(ownT + (size_t)(t + 1) * ownStr + tid, bits, (uint32_t)(t + 1));
      }
      __syncthreads();
    }
    return;
  }

  // ================= wg0: L1 + L3 + output =================
  uint32_t W1x, W1h[76];      // L1 row (arch VGPRs)
  uint32_t Wex[80];           // AGPR resident; by tid: [0,92) L1-extra; 92/93 Wl; [104,512) L3 half-row
  {
    const uint32_t* s1 = ws + O_W1 + (size_t)tid * 80;
    W1x = s1[0];
#pragma unroll
    for (int j = 0; j < 76; ++j) W1h[j] = s1[4 + j];
  }
  {
    uint32_t tmp[80];
#pragma unroll
    for (int j = 0; j < 80; ++j) tmp[j] = 0u;
    if (tid < 92) {
      const uint32_t* s2 = ws + O_W1B + (size_t)tid * 80;
      tmp[0] = s2[0];
#pragma unroll
      for (int j = 0; j < 76; ++j) tmp[1 + j] = s2[4 + j];
    } else if (tid == 92 || tid == 93) {
      const uint32_t* s2 = ws + O_WY + (size_t)(tid - 92) * 32;
#pragma unroll
      for (int j = 0; j < 32; ++j) tmp[j] = s2[j];
    } else if (tid >= 104) {
      const uint32_t* s2 = ws + O_W3 + (size_t)(tid - 104) * 80;
#pragma unroll
      for (int j = 0; j < 80; ++j) tmp[j] = s2[j];
    }
#pragma unroll
    for (int j = 0; j < 80; ++j) Wex[j] = aput(tmp[j]);
  }
  float b1a = bih1[tid] + bhh1[tid];                       // row = tid (<512)
  float b1b = (tid < 92) ? (bih1[512 + tid] + bhh1[512 + tid]) : 0.f;
  float b3 = 0.f;
  if (tid >= 104 && ((tid - 104) & 1) == 0) {
    int r3 = (tid - 104) >> 1;
    b3 = bih3[r3] + bhh3[r3];
  }
  float by = (tid == 92 || tid == 93) ? bl[tid - 92] : 0.f;
  float c1 = 0.f, c3 = 0.f;
  if (tid < 152) h1L[tid] = 0;
  if (tid < 320) Vb3[tid] = 0;
  __syncthreads();

  // ---- Phase A: blast entire main-phase L1 (self-recurrent; x known) ----
#pragma unroll 1
  for (int t = 0; t < T_MAIN; ++t) {
    uint32_t xin = ws[O_X + t];
    const uint4* Hp = (const uint4*)h1L;
    {
      float g0 = fdot2(W1x, xin, b1a), g1 = 0.f, g2 = 0.f, g3 = 0.f;
#pragma unroll
      for (int j = 0; j < 19; ++j) {
        uint4 hv = Hp[j];
        g0 = fdot2(W1h[4 * j + 0], hv.x, g0);
        g1 = fdot2(W1h[4 * j + 1], hv.y, g1);
        g2 = fdot2(W1h[4 * j + 2], hv.z, g2);
        g3 = fdot2(W1h[4 * j + 3], hv.w, g3);
      }
      G[tid] = (g0 + g1) + (g2 + g3);
    }
    if (tid < 92) {
      float g0 = fdot2(aget(Wex[0]), xin, b1b), g1 = 0.f, g2 = 0.f, g3 = 0.f;
#pragma unroll
      for (int j = 0; j < 19; ++j) {
        uint4 hv = Hp[j];
        g0 = fdot2(aget(Wex[1 + 4 * j]), hv.x, g0);
        g1 = fdot2(aget(Wex[2 + 4 * j]), hv.y, g1);
        g2 = fdot2(aget(Wex[3 + 4 * j]), hv.z, g2);
        g3 = fdot2(aget(Wex[4 + 4 * j]), hv.w, g3);
      }
      G[512 + tid] = (g0 + g1) + (g2 + g3);
    }
    __syncthreads();
    if (tid < 151) {
      float gi = sigm(G[tid]), gf = sigm(G[151 + tid]);
      float gg = tanhfast(G[302 + tid]), go = sigm(G[453 + tid]);
      c1 = gf * c1 + gi * gg;
      uint16_t bits = f16bits(go * tanhfast(c1));
      h1L[tid] = bits;
      pubslot(ws + O_H1T + (size_t)(t + 1) * 152 + tid, bits, (uint32_t)(t + 1));
    }
    __syncthreads();
  }

  // ---- Phase B: main-phase L3 + y, streaming pair's h2 traces ----
#pragma unroll 1
  for (int t = 0; t < T_MAIN; ++t) {
    if (tid < 126) {
      uint32_t v = pollslot(ws + O_H2AT + (size_t)(t + 1) * 126 + tid, (uint32_t)(t + 1), &bailS);
      Vb3[tid] = (uint16_t)(v >> 16);
    } else if (tid >= 128 && tid < 253) {
      int j = tid - 128;
      uint32_t v = pollslot(ws + O_H2BT + (size_t)(t + 1) * 125 + j, (uint32_t)(t + 1), &bailS);
      Vb3[128 + j] = (uint16_t)(v >> 16);
    }
    __syncthreads();
    if (tid >= 104) {
      int it = tid - 104, r3 = it >> 1, hf = it & 1;
      const uint4* V = (const uint4*)Vb3 + hf * 20;
      float g0 = 0.f, g1 = 0.f, g2 = 0.f, g3 = 0.f;
#pragma unroll
      for (int j = 0; j < 20; ++j) {
        uint4 hv = V[j];
        g0 = fdot2(aget(Wex[4 * j + 0]), hv.x, g0);
        g1 = fdot2(aget(Wex[4 * j + 1]), hv.y, g1);
        g2 = fdot2(aget(Wex[4 * j + 2]), hv.z, g2);
        g3 = fdot2(aget(Wex[4 * j + 3]), hv.w, g3);
      }
      float s = (g0 + g1) + (g2 + g3);
      s += __shfl_xor(s, 1);
      if (!hf) G[r3] = s + b3;
    }
    __syncthreads();
    if (tid < 51) {
      float gi = sigm(G[tid]), gf = sigm(G[51 + tid]);
      float gg = tanhfast(G[102 + tid]), go = sigm(G[153 + tid]);
      c3 = gf * c3 + gi * gg;
      Vb3[256 + tid] = f16bits(go * tanhfast(c3));
    }
    __syncthreads();
    if (tid == 92 || tid == 93) {
      const uint4* V = (const uint4*)Vb3 + 32;   // h3 slots (u16 256..319)
      float g0 = by, g1 = 0.f, g2 = 0.f, g3 = 0.f;
#pragma unroll
      for (int j = 0; j < 8; ++j) {
        uint4 hv = V[j];
        g0 = fdot2(aget(Wex[4 * j + 0]), hv.x, g0);
        g1 = fdot2(aget(Wex[4 * j + 1]), hv.y, g1);
        g2 = fdot2(aget(Wex[4 * j + 2]), hv.z, g2);
        g3 = fdot2(aget(Wex[4 * j + 3]), hv.w, g3);
      }
      float y = (g0 + g1) + (g2 + g3);
      out[2 * t + (tid - 92)] = y;
      float y1 = __shfl(y, 29);          // tid 93 = lane 29 of wave 1
      if (tid == 92) yL = packf16(y, y1);
    }
    // no barrier needed: next stage writes Vb3[0,253) (disjoint from y's reads [256,320))
  }
  __syncthreads();

  // ---- Phase C: future steps (serial chain, y fed back) ----
#pragma unroll 1
  for (int t = T_MAIN; t < T_TOT; ++t) {
    uint32_t xin = yL;
    const uint4* Hp = (const uint4*)h1L;
    {
      float g0 = fdot2(W1x, xin, b1a), g1 = 0.f, g2 = 0.f, g3 = 0.f;
#pragma unroll
      for (int j = 0; j < 19; ++j) {
        uint4 hv = Hp[j];
        g0 = fdot2(W1h[4 * j + 0], hv.x, g0);
        g1 = fdot2(W1h[4 * j + 1], hv.y, g1);
        g2 = fdot2(W1h[4 * j + 2], hv.z, g2);
        g3 = fdot2(W1h[4 * j + 3], hv.w, g3);
      }
      G[tid] = (g0 + g1) + (g2 + g3);
    }
    if (tid < 92) {
      float g0 = fdot2(aget(Wex[0]), xin, b1b), g1 = 0.f, g2 = 0.f, g3 = 0.f;
#pragma unroll
      for (int j = 0; j < 19; ++j) {
        uint4 hv = Hp[j];
        g0 = fdot2(aget(Wex[1 + 4 * j]), hv.x, g0);
        g1 = fdot2(aget(Wex[2 + 4 * j]), hv.y, g1);
        g2 = fdot2(aget(Wex[3 + 4 * j]), hv.z, g2);
        g3 = fdot2(aget(Wex[4 + 4 * j]), hv.w, g3);
      }
      G[512 + tid] = (g0 + g1) + (g2 + g3);
    }
    __syncthreads();
    if (tid < 151) {
      float gi = sigm(G[tid]), gf = sigm(G[151 + tid]);
      float gg = tanhfast(G[302 + tid]), go = sigm(G[453 + tid]);
      c1 = gf * c1 + gi * gg;
      uint16_t bits = f16bits(go * tanhfast(c1));
      h1L[tid] = bits;
      pubslot(ws + O_H1T + (size_t)(t + 1) * 152 + tid, bits, (uint32_t)(t + 1));
    }
    __syncthreads();
    // L3 stage: wait for pair's h2(t)
    if (tid < 126) {
      uint32_t v = pollslot(ws + O_H2AT + (size_t)(t + 1) * 126 + tid, (uint32_t)(t + 1), &bailS);
      Vb3[tid] = (uint16_t)(v >> 16);
    } else if (tid >= 128 && tid < 253) {
      int j = tid - 128;
      uint32_t v = pollslot(ws + O_H2BT + (size_t)(t + 1) * 125 + j, (uint32_t)(t + 1), &bailS);
      Vb3[128 + j] = (uint16_t)(v >> 16);
    }
    __syncthreads();
    if (tid >= 104) {
      int it = tid - 104, r3 = it >> 1, hf = it & 1;
      const uint4* V = (const uint4*)Vb3 + hf * 20;
      float g0 = 0.f, g1 = 0.f, g2 = 0.f, g3 = 0.f;
#pragma unroll
      for (int j = 0; j < 20; ++j) {
        uint4 hv = V[j];
        g0 = fdot2(aget(Wex[4 * j + 0]), hv.x, g0);
        g1 = fdot2(aget(Wex[4 * j + 1]), hv.y, g1);
        g2 = fdot2(aget(Wex[4 * j + 2]), hv.z, g2);
        g3 = fdot2(aget(Wex[4 * j + 3]), hv.w, g3);
      }
      float s = (g0 + g1) + (g2 + g3);
      s += __shfl_xor(s, 1);
      if (!hf) G[r3] = s + b3;
    }
    __syncthreads();
    if (tid < 51) {
      float gi = sigm(G[tid]), gf = sigm(G[51 + tid]);
      float gg = tanhfast(G[102 + tid]), go = sigm(G[153 + tid]);
      c3 = gf * c3 + gi * gg;
      Vb3[256 + tid] = f16bits(go * tanhfast(c3));
    }
    __syncthreads();
    if (tid == 92 || tid == 93) {
      const uint4* V = (const uint4*)Vb3 + 32;   // h3 slots
      float g0 = by, g1 = 0.f, g2 = 0.f, g3 = 0.f;
#pragma unroll
      for (int j = 0; j < 8; ++j) {
        uint4 hv = V[j];
        g0 = fdot2(aget(Wex[4 * j + 0]), hv.x, g0);
        g1 = fdot2(aget(Wex[4 * j + 1]), hv.y, g1);
        g2 = fdot2(aget(Wex[4 * j + 2]), hv.z, g2);
        g3 = fdot2(aget(Wex[4 * j + 3]), hv.w, g3);
      }
      float y = (g0 + g1) + (g2 + g3);
      out[2 * t + (tid - 92)] = y;
      float y1 = __shfl(y, 29);
      if (tid == 92) yL = packf16(y, y1);
    }
    __syncthreads();   // yL must be visible to next iteration's L1
  }
}

extern "C" void kernel_launch(void* const* d_in, const int* in_sizes, int n_in,
                              void* d_out, int out_size, void* d_ws, size_t ws_size,
                              hipStream_t stream) {
  (void)in_sizes; (void)n_in; (void)out_size; (void)ws_size;
  const float* x    = (const float*)d_in[0];
  const float* Wih1 = (const float*)d_in[1];
  const float* Whh1 = (const float*)d_in[2];
  const float* bih1 = (const float*)d_in[3];
  const float* bhh1 = (const float*)d_in[4];
  const float* Wih2 = (const float*)d_in[5];
  const float* Whh2 = (const float*)d_in[6];
  const float* bih2 = (const float*)d_in[7];
  const float* bhh2 = (const float*)d_in[8];
  const float* Wih3 = (const float*)d_in[9];
  const float* Whh3 = (const float*)d_in[10];
  const float* bih3 = (const float*)d_in[11];
  const float* bhh3 = (const float*)d_in[12];
  const float* Wl   = (const float*)d_in[13];
  const float* bl   = (const float*)d_in[14];

  uint32_t* ws = (uint32_t*)d_ws;   // ~9.4 MB

  prep<<<2102, 64, 0, stream>>>(x, Wih1, Whh1, Wih2, Whh2, Wih3, Whh3, Wl, ws);
  lstm3<<<24, 512, 0, stream>>>(ws, bih1, bhh1, bih2, bhh2, bih3, bhh3, bl,
                                (float*)d_out);
}